// Round 3
// baseline (137.486 us; speedup 1.0000x reference)
//
#include <hip/hip_runtime.h>
#include <math.h>

#define N_COLS 1024
#define NRINGS 8

// ---- geometry: 32 threads/row, 32 cols/thread ----
#define TPR    32
#define CHUNK  32
#define ROWS_PER_BLOCK 8          // 256 threads / 32 tpr

// ws layout (floats)
#define F_OFF   16384             // CS: 8*512 float4 = 16384 floats (64 KB)
#define A_OFF   24576             // F : 8*256 float4 =  8192 floats (32 KB)
#define AUX_OFF 24832             // A : 8*32 floats
#define WS_FLOATS 24848           // AUX: 8 float2

// =====================  setup: build angle tables  ======================
// grid = 8 blocks (one ring each), 256 threads, fully parallel (no serial-32
// chain, no local arrays -> no scratch).  Per ring r:
//   CS  [(r*16 + j/2)*32 + t] : float4 (c_j,s_j,c_{j+1},s_{j+1}), k = t*32+j
//   F   [(r*8  + j/4)*32 + t] : float4 f_j = c_j * prod_{l>j in chunk}(-s_l)
//   A   [r*32 + t]            : prod_j(-s_j) over chunk t
//   AUX [r]                   : real (c,s) at k=1023 (table entry doctored to
//                               (0,-1) = exact no-op chain step)
__global__ __launch_bounds__(256)
void ced_setup(const float* __restrict__ ae,
               const float* __restrict__ ad,
               float* __restrict__ ws)
{
    __shared__ float2 ls[N_COLS];
    const int r   = blockIdx.x;
    const int tid = threadIdx.x;
    const float* ang = (r < 4) ? (ae + (r << 10)) : (ad + ((r - 4) << 10));

    #pragma unroll
    for (int m = 0; m < 4; ++m) {
        int k = (m << 8) + tid;
        float sv, cv;
        sincosf(ang[k], &sv, &cv);
        if (k == N_COLS - 1) {
            ((float2*)(ws + AUX_OFF))[r] = make_float2(cv, sv);
            cv = 0.f; sv = -1.f;          // doctored: no-op step
        }
        ls[k] = make_float2(cv, sv);
    }
    __syncthreads();

    // thread owns chunk t, sub-segment q (4 elements j = 4q..4q+3)
    const int t = tid >> 3;
    const int q = tid & 7;
    const int j0 = t * CHUNK + 4 * q;
    float2 e0 = ls[j0], e1 = ls[j0+1], e2 = ls[j0+2], e3 = ls[j0+3];

    // paired (c,s) table
    float4* CSw = (float4*)ws;
    CSw[(r*16 + 2*q    )*32 + t] = make_float4(e0.x, e0.y, e1.x, e1.y);
    CSw[(r*16 + 2*q + 1)*32 + t] = make_float4(e2.x, e2.y, e3.x, e3.y);

    // local suffix products within the 4-segment
    float f3 = e3.x;       float P = -e3.y;
    float f2 = e2.x * P;   P *= -e2.y;
    float f1 = e1.x * P;   P *= -e1.y;
    float f0 = e0.x * P;   P *= -e0.y;     // P = prod over segment

    // inclusive suffix product over the 8 segments of this chunk
    // (8 q-lanes are contiguous within the wave)
    float ip = P;
    #pragma unroll
    for (int d = 1; d < 8; d <<= 1) {
        float tmp = __shfl_down(ip, d);
        if (q + d < 8) ip *= tmp;
    }
    float ex = __shfl_down(ip, 1);         // exclusive suffix
    if (q == 7) ex = 1.f;
    f0 *= ex; f1 *= ex; f2 *= ex; f3 *= ex;

    float4* Fw = (float4*)(ws + F_OFF);
    Fw[(r*8 + q)*32 + t] = make_float4(f0, f1, f2, f3);
    if (q == 0) ws[A_OFF + r*TPR + t] = ip;   // full chunk product
}

// =====================  main: fused enc->blend->dec  ====================
__global__ __launch_bounds__(256, 4)
void ced_main(const float* __restrict__ x,
              const float* __restrict__ ws,
              const float* __restrict__ hw,
              const float* __restrict__ hs,
              float* __restrict__ out, int B)
{
    const float4* CS  = (const float4*)ws;
    const float4* F   = (const float4*)(ws + F_OFF);
    const float*  A   = ws + A_OFF;
    const float2* AUX = (const float2*)(ws + AUX_OFF);

    const int tid  = threadIdx.x;
    const int lane = tid & 63;
    const int t    = lane & 31;           // chunk index within row
    const int g    = lane >> 5;           // 2 rows per wave
    const int groupBase = lane & 32;
    const int row  = blockIdx.x * ROWS_PER_BLOCK + (tid >> 6) * 2 + g;

    float y[CHUNK];
    const float4* xp = (const float4*)(x + (size_t)row * N_COLS + t * CHUNK);
    #pragma unroll
    for (int i = 0; i < 8; ++i) {
        float4 v = xp[i];
        y[4*i] = v.x; y[4*i+1] = v.y; y[4*i+2] = v.z; y[4*i+3] = v.w;
    }

    const float w   = 1.f / (1.f + expf(-hw[0]));
    const float omw = 1.f - w;

    #pragma unroll 1
    for (int r = 0; r < NRINGS; ++r) {
        if (r == 4) {                     // bottleneck blend + output 0
            float4* ob = (float4*)(out + (size_t)row * N_COLS + t * CHUNK);
            const float4* hp = (const float4*)(hs + t * CHUNK);
            #pragma unroll
            for (int i = 0; i < 8; ++i) {
                float4 h = hp[i];
                float4 bn;
                bn.x = fmaf(omw, y[4*i+0], w * h.x);
                bn.y = fmaf(omw, y[4*i+1], w * h.y);
                bn.z = fmaf(omw, y[4*i+2], w * h.z);
                bn.w = fmaf(omw, y[4*i+3], w * h.w);
                ob[i] = bn;
                y[4*i+0] = bn.x; y[4*i+1] = bn.y; y[4*i+2] = bn.z; y[4*i+3] = bn.w;
            }
        }

        // ---- prefetch the whole ring's CS table BEFORE the serial chain ----
        const float4* csr = CS + r * 512 + t;
        float4 cs_all[16];
        #pragma unroll
        for (int jp = 0; jp < 16; ++jp) cs_all[jp] = csr[jp * 32];

        const float2 cN = AUX[r];
        float y0 = __shfl(y[0],       groupBase);
        float yN = __shfl(y[CHUNK-1], groupBase + 31);
        float Cinit = cN.x * yN - cN.y * y0;      // carry entering the chain
        float x0n   = fmaf(cN.y, yN, cN.x * y0);  // updated slot 0
        if (t == 0) y[0] = x0n;

        // ---- pass 1: local chain, carry_in = 0 (all operands in regs) ----
        float carry = 0.f, ztmp = 0.f;
        #pragma unroll
        for (int jp = CHUNK/2 - 1; jp >= 0; --jp) {
            float4 cs4 = cs_all[jp];              // (c_j0,s_j0,c_j1,s_j1)
            const int j1 = 2*jp + 1;
            float z1 = fmaf(cs4.w, y[j1], cs4.z * carry);
            carry    = fmaf(-cs4.w, carry, cs4.z * y[j1]);
            if (j1 == CHUNK - 1) ztmp = z1; else y[j1+1] = z1;
            const int j0 = 2*jp;
            float z0s = fmaf(cs4.y, y[j0], cs4.x * carry);
            carry     = fmaf(-cs4.y, carry, cs4.x * y[j0]);
            y[j0+1] = z0s;
        }

        // ---- prefetch F (consumed after scan; latency hides behind it) ----
        const float4* fr = F + r * 256 + t;
        float4 f_all[8];
        #pragma unroll
        for (int qi = 0; qi < 8; ++qi) f_all[qi] = fr[qi * 32];

        // ---- affine suffix scan over 32 lanes (carry flows 31 -> 0) ----
        float sa = A[r*32 + t];
        float sb = carry;
        #pragma unroll
        for (int d = 1; d < TPR; d <<= 1) {
            float a2 = __shfl_down(sa, d);
            float b2 = __shfl_down(sb, d);
            if (t + d < TPR) { sb = fmaf(sa, b2, sb); sa *= a2; }
        }
        float ea = __shfl_down(sa, 1), eb = __shfl_down(sb, 1);
        float zfirst = fmaf(sa, Cinit, sb);       // lane0: final z[0]
        float Cin = (t == TPR - 1) ? Cinit : fmaf(ea, Cinit, eb);

        // ---- pass 2: independent fix-up with precomputed f ----
        #pragma unroll
        for (int qi = CHUNK/4 - 1; qi >= 0; --qi) {
            float4 f4 = f_all[qi];
            const int j = 4*qi;
            if (j + 3 == CHUNK - 1) ztmp   = fmaf(f4.w, Cin, ztmp);
            else                    y[j+4] = fmaf(f4.w, Cin, y[j+4]);
            y[j+3] = fmaf(f4.z, Cin, y[j+3]);
            y[j+2] = fmaf(f4.y, Cin, y[j+2]);
            y[j+1] = fmaf(f4.x, Cin, y[j+1]);
        }

        float up = __shfl_up(ztmp, 1);            // lane t-1's top -> slot 32t
        y[0] = (t == 0) ? zfirst : up;
    }

    float4* oo = (float4*)(out + (size_t)B * N_COLS + (size_t)row * N_COLS + t * CHUNK);
    #pragma unroll
    for (int i = 0; i < 8; ++i)
        oo[i] = make_float4(y[4*i], y[4*i+1], y[4*i+2], y[4*i+3]);
}

// ==================  fallback (self-contained, ws-free)  =================
__global__ __launch_bounds__(256, 2)
void ced_fallback(const float* __restrict__ x,
                  const float* __restrict__ ae,
                  const float* __restrict__ ad,
                  const float* __restrict__ hw,
                  const float* __restrict__ hs,
                  float* __restrict__ out, int B)
{
    __shared__ float2 s_cs[NRINGS * 64 * 16];
    __shared__ float  s_A [NRINGS * 16];
    __shared__ float2 s_aux[NRINGS];

    const int tid = threadIdx.x;
    for (int i = 0; i < 32; ++i) {
        int idx = i * 256 + tid;
        int r   = idx >> 10;
        int k   = idx & 1023;
        const float* ang = (r < 4) ? (ae + (r << 10)) : (ad + ((r - 4) << 10));
        float sv, cv;
        sincosf(ang[k], &sv, &cv);
        int t = k >> 6, j = k & 63;
        float2 e = make_float2(cv, sv);
        if (k == 1023) { s_aux[r] = e; e = make_float2(0.f, -1.f); }
        s_cs[(r * 64 + j) * 16 + t] = e;
    }
    __syncthreads();
    if (tid < NRINGS * 16) {
        int r = tid >> 4, t = tid & 15;
        float p = 1.f;
        for (int j = 0; j < 64; ++j) p *= -s_cs[(r * 64 + j) * 16 + t].y;
        s_A[tid] = p;
    }
    __syncthreads();

    const int lane      = tid & 63;
    const int g         = lane >> 4;
    const int t         = lane & 15;
    const int groupBase = lane & 48;
    const int row       = blockIdx.x * 16 + (tid >> 6) * 4 + g;

    const float* xr = x + (size_t)row * N_COLS + t * 64;
    float y[64];
    #pragma unroll
    for (int i = 0; i < 16; ++i) {
        float4 v = ((const float4*)xr)[i];
        y[4*i] = v.x; y[4*i+1] = v.y; y[4*i+2] = v.z; y[4*i+3] = v.w;
    }
    const float w   = 1.f / (1.f + expf(-hw[0]));
    const float omw = 1.f - w;

    for (int r = 0; r < NRINGS; ++r) {
        if (r == 4) {
            float4* ob = (float4*)(out + (size_t)row * N_COLS + t * 64);
            const float4* hp = (const float4*)(hs + t * 64);
            #pragma unroll
            for (int i = 0; i < 16; ++i) {
                float4 h = hp[i];
                float4 bn;
                bn.x = fmaf(omw, y[4*i+0], w * h.x);
                bn.y = fmaf(omw, y[4*i+1], w * h.y);
                bn.z = fmaf(omw, y[4*i+2], w * h.z);
                bn.w = fmaf(omw, y[4*i+3], w * h.w);
                ob[i] = bn;
                y[4*i+0] = bn.x; y[4*i+1] = bn.y; y[4*i+2] = bn.z; y[4*i+3] = bn.w;
            }
        }
        const float2* csr = s_cs + r * 64 * 16;
        const float2  cN  = s_aux[r];
        float y0 = __shfl(y[0],  groupBase);
        float yN = __shfl(y[63], groupBase + 15);
        float Cinit = cN.x * yN - cN.y * y0;
        float x0n   = fmaf(cN.y, yN, cN.x * y0);
        if (t == 0) y[0] = x0n;

        float carry = 0.f, ztmp = 0.f;
        #pragma unroll
        for (int j = 63; j >= 0; --j) {
            float2 cs = csr[j * 16 + t];
            float z   = fmaf(cs.y, y[j], cs.x * carry);
            carry     = fmaf(-cs.y, carry, cs.x * y[j]);
            if (j == 63) ztmp = z; else y[j + 1] = z;
        }
        float sa = s_A[r * 16 + t], sb = carry;
        #pragma unroll
        for (int d = 1; d < 16; d <<= 1) {
            float a2 = __shfl_down(sa, d);
            float b2 = __shfl_down(sb, d);
            if (t + d < 16) { sb = fmaf(sa, b2, sb); sa *= a2; }
        }
        float ea = __shfl_down(sa, 1);
        float eb = __shfl_down(sb, 1);
        float z0  = fmaf(sa, Cinit, sb);
        float Cin = (t == 15) ? Cinit : fmaf(ea, Cinit, eb);

        float P = 1.f;
        #pragma unroll
        for (int j = 63; j >= 0; --j) {
            float2 cs = csr[j * 16 + t];
            float f = cs.x * P;
            P = -cs.y * P;
            if (j == 63) ztmp = fmaf(f, Cin, ztmp);
            else         y[j + 1] = fmaf(f, Cin, y[j + 1]);
        }
        float up = __shfl_up(ztmp, 1);
        y[0] = (t == 0) ? z0 : up;
    }

    float4* oo = (float4*)(out + (size_t)B * N_COLS + (size_t)row * N_COLS + t * 64);
    #pragma unroll
    for (int i = 0; i < 16; ++i)
        oo[i] = make_float4(y[4*i], y[4*i+1], y[4*i+2], y[4*i+3]);
}

// ============================  launcher  ================================
extern "C" void kernel_launch(void* const* d_in, const int* in_sizes, int n_in,
                              void* d_out, int out_size, void* d_ws, size_t ws_size,
                              hipStream_t stream) {
    const float* x  = (const float*)d_in[0];
    const float* ae = (const float*)d_in[1];
    const float* ad = (const float*)d_in[2];
    const float* hw = (const float*)d_in[3];
    const float* hs = (const float*)d_in[4];
    float* out = (float*)d_out;
    const int B = in_sizes[0] / N_COLS;          // 8192

    if (ws_size >= WS_FLOATS * sizeof(float)) {
        hipLaunchKernelGGL(ced_setup, dim3(NRINGS), dim3(256), 0, stream,
                           ae, ad, (float*)d_ws);
        hipLaunchKernelGGL(ced_main, dim3(B / ROWS_PER_BLOCK), dim3(256), 0, stream,
                           x, (const float*)d_ws, hw, hs, out, B);
    } else {
        hipLaunchKernelGGL(ced_fallback, dim3(B / 16), dim3(256), 0, stream,
                           x, ae, ad, hw, hs, out, B);
    }
}

// Round 4
// 136.701 us; speedup vs baseline: 1.0057x; 1.0057x over previous
//
#include <hip/hip_runtime.h>
#include <math.h>

#define N_COLS 1024
#define NRINGS 8

// ---- geometry: 32 threads/row, 32 cols/thread, 2 rows per thread ----
#define TPR    32
#define CHUNK  32
#define PAIRS_PER_BLOCK 8         // 256 threads / 32 lanes-per-pair -> 16 rows/block

// ws layout (floats)
#define F_OFF   16384             // CS: 8*512 float4 = 16384 floats (64 KB)
#define A_OFF   24576             // F : 8*256 float4 =  8192 floats (32 KB)
#define AUX_OFF 24832             // A : 8*32 floats
#define WS_FLOATS 24848           // AUX: 8 float2

// =====================  setup: build angle tables  ======================
// grid = 32 blocks (4 per ring, 256 angles each; chunks are 32 angles so each
// block is self-contained for chunk suffix-products). 1 sincos per thread.
//   CS  [(r*16 + j/2)*32 + t] : float4 (c_j,s_j,c_{j+1},s_{j+1}), k = t*32+j
//   F   [(r*8  + j/4)*32 + t] : float4 f_j = c_j * prod_{l>j in chunk}(-s_l)
//   A   [r*32 + t]            : prod_j(-s_j) over chunk t
//   AUX [r]                   : real (c,s) at k=1023 (table entry doctored to
//                               (0,-1) = exact no-op chain step)
__global__ __launch_bounds__(256)
void ced_setup(const float* __restrict__ ae,
               const float* __restrict__ ad,
               float* __restrict__ ws)
{
    __shared__ float2 ls[256];
    const int r   = blockIdx.x >> 2;
    const int b   = blockIdx.x & 3;
    const int tid = threadIdx.x;
    const int k   = (b << 8) + tid;
    const float* ang = (r < 4) ? (ae + (r << 10)) : (ad + ((r - 4) << 10));

    float sv, cv;
    sincosf(ang[k], &sv, &cv);
    if (k == N_COLS - 1) {
        ((float2*)(ws + AUX_OFF))[r] = make_float2(cv, sv);
        cv = 0.f; sv = -1.f;              // doctored: no-op step
    }
    ls[tid] = make_float2(cv, sv);
    __syncthreads();

    if (!(tid & 1)) {                     // paired (c,s) table
        float2 e0 = ls[tid], e1 = ls[tid + 1];
        int t  = k >> 5;
        int jp = (k & 31) >> 1;
        ((float4*)ws)[(r*16 + jp)*32 + t] = make_float4(e0.x, e0.y, e1.x, e1.y);
    }

    if (tid < 64) {                       // F and A via 3-round shfl product-scan
        const int lt = tid >> 3;          // local chunk 0..7
        const int q  = tid & 7;           // 4-element sub-segment
        const int t  = (b << 3) + lt;     // global chunk
        const int j0 = lt * CHUNK + 4 * q;
        float2 e0 = ls[j0], e1 = ls[j0+1], e2 = ls[j0+2], e3 = ls[j0+3];

        float f3 = e3.x;       float P = -e3.y;
        float f2 = e2.x * P;   P *= -e2.y;
        float f1 = e1.x * P;   P *= -e1.y;
        float f0 = e0.x * P;   P *= -e0.y;

        float ip = P;                     // inclusive suffix product over segments
        #pragma unroll
        for (int d = 1; d < 8; d <<= 1) {
            float tmp = __shfl_down(ip, d);
            if (q + d < 8) ip *= tmp;
        }
        float ex = __shfl_down(ip, 1);
        if (q == 7) ex = 1.f;
        f0 *= ex; f1 *= ex; f2 *= ex; f3 *= ex;

        ((float4*)(ws + F_OFF))[(r*8 + q)*32 + t] = make_float4(f0, f1, f2, f3);
        if (q == 0) ws[A_OFF + r*TPR + t] = ip;
    }
}

// =====================  main: fused enc->blend->dec  ====================
// 2 rows per thread: table loads amortized, 2x ILP in chain+scan, and grid
// 512 = 2 blocks/CU allows __launch_bounds__(256,2) -> 256-VGPR budget so the
// cs_all/f_all prefetches actually stay hoisted (round-3 failure: budget 128
// forced the scheduler to sink them).
__global__ __launch_bounds__(256, 2)
void ced_main(const float* __restrict__ x,
              const float* __restrict__ ws,
              const float* __restrict__ hw,
              const float* __restrict__ hs,
              float* __restrict__ out, int B)
{
    const float4* CS  = (const float4*)ws;
    const float4* F   = (const float4*)(ws + F_OFF);
    const float*  A   = ws + A_OFF;
    const float2* AUX = (const float2*)(ws + AUX_OFF);

    const int tid  = threadIdx.x;
    const int lane = tid & 63;
    const int t    = lane & 31;           // chunk index within row
    const int groupBase = lane & 32;
    const int pair = blockIdx.x * PAIRS_PER_BLOCK + (tid >> 5);

    const size_t rowA = (size_t)(2 * pair) * N_COLS;
    const size_t rowB = rowA + N_COLS;

    float ya[CHUNK], yb[CHUNK];
    {
        const float4* xa = (const float4*)(x + rowA + t * CHUNK);
        const float4* xb = (const float4*)(x + rowB + t * CHUNK);
        #pragma unroll
        for (int i = 0; i < 8; ++i) {
            float4 va = xa[i], vb = xb[i];
            ya[4*i] = va.x; ya[4*i+1] = va.y; ya[4*i+2] = va.z; ya[4*i+3] = va.w;
            yb[4*i] = vb.x; yb[4*i+1] = vb.y; yb[4*i+2] = vb.z; yb[4*i+3] = vb.w;
        }
    }

    const float w   = 1.f / (1.f + expf(-hw[0]));
    const float omw = 1.f - w;

    #pragma unroll 1
    for (int r = 0; r < NRINGS; ++r) {
        if (r == 4) {                     // bottleneck blend + output 0 (both rows)
            float4* oa = (float4*)(out + rowA + t * CHUNK);
            float4* ob = (float4*)(out + rowB + t * CHUNK);
            const float4* hp = (const float4*)(hs + t * CHUNK);
            #pragma unroll
            for (int i = 0; i < 8; ++i) {
                float4 h = hp[i];
                float4 na, nb;
                na.x = fmaf(omw, ya[4*i+0], w * h.x);
                na.y = fmaf(omw, ya[4*i+1], w * h.y);
                na.z = fmaf(omw, ya[4*i+2], w * h.z);
                na.w = fmaf(omw, ya[4*i+3], w * h.w);
                nb.x = fmaf(omw, yb[4*i+0], w * h.x);
                nb.y = fmaf(omw, yb[4*i+1], w * h.y);
                nb.z = fmaf(omw, yb[4*i+2], w * h.z);
                nb.w = fmaf(omw, yb[4*i+3], w * h.w);
                oa[i] = na; ob[i] = nb;
                ya[4*i+0] = na.x; ya[4*i+1] = na.y; ya[4*i+2] = na.z; ya[4*i+3] = na.w;
                yb[4*i+0] = nb.x; yb[4*i+1] = nb.y; yb[4*i+2] = nb.z; yb[4*i+3] = nb.w;
            }
        }

        // ---- prefetch the ring's CS table (shared by both rows) ----
        const float4* csr = CS + r * 512 + t;
        float4 cs_all[16];
        #pragma unroll
        for (int jp = 0; jp < 16; ++jp) cs_all[jp] = csr[jp * 32];

        const float2 cN = AUX[r];
        float y0a = __shfl(ya[0],       groupBase);
        float yNa = __shfl(ya[CHUNK-1], groupBase + 31);
        float y0b = __shfl(yb[0],       groupBase);
        float yNb = __shfl(yb[CHUNK-1], groupBase + 31);
        float CinitA = cN.x * yNa - cN.y * y0a;
        float CinitB = cN.x * yNb - cN.y * y0b;
        float x0nA   = fmaf(cN.y, yNa, cN.x * y0a);
        float x0nB   = fmaf(cN.y, yNb, cN.x * y0b);
        if (t == 0) { ya[0] = x0nA; yb[0] = x0nB; }

        // ---- pass 1: two independent local chains (carry_in = 0) ----
        float carA = 0.f, carB = 0.f, ztA = 0.f, ztB = 0.f;
        #pragma unroll
        for (int jp = CHUNK/2 - 1; jp >= 0; --jp) {
            float4 cs4 = cs_all[jp];              // (c_j0,s_j0,c_j1,s_j1)
            const int j1 = 2*jp + 1;
            float z1a = fmaf(cs4.w, ya[j1], cs4.z * carA);
            float z1b = fmaf(cs4.w, yb[j1], cs4.z * carB);
            carA = fmaf(-cs4.w, carA, cs4.z * ya[j1]);
            carB = fmaf(-cs4.w, carB, cs4.z * yb[j1]);
            if (j1 == CHUNK - 1) { ztA = z1a; ztB = z1b; }
            else                 { ya[j1+1] = z1a; yb[j1+1] = z1b; }
            const int j0 = 2*jp;
            float z0a = fmaf(cs4.y, ya[j0], cs4.x * carA);
            float z0b = fmaf(cs4.y, yb[j0], cs4.x * carB);
            carA = fmaf(-cs4.y, carA, cs4.x * ya[j0]);
            carB = fmaf(-cs4.y, carB, cs4.x * yb[j0]);
            ya[j0+1] = z0a; yb[j0+1] = z0b;
        }

        // ---- prefetch F (consumed after the scan) ----
        const float4* fr = F + r * 256 + t;
        float4 f_all[8];
        #pragma unroll
        for (int qi = 0; qi < 8; ++qi) f_all[qi] = fr[qi * 32];

        // ---- affine suffix scan, sa shared across the two rows ----
        float sa = A[r*32 + t];
        float sbA = carA, sbB = carB;
        #pragma unroll
        for (int d = 1; d < TPR; d <<= 1) {
            float a2  = __shfl_down(sa,  d);
            float b2a = __shfl_down(sbA, d);
            float b2b = __shfl_down(sbB, d);
            if (t + d < TPR) {
                sbA = fmaf(sa, b2a, sbA);
                sbB = fmaf(sa, b2b, sbB);
                sa *= a2;
            }
        }
        float ea  = __shfl_down(sa,  1);
        float ebA = __shfl_down(sbA, 1);
        float ebB = __shfl_down(sbB, 1);
        float zfA = fmaf(sa, CinitA, sbA);        // lane0: final z[0]
        float zfB = fmaf(sa, CinitB, sbB);
        float CinA = (t == TPR - 1) ? CinitA : fmaf(ea, CinitA, ebA);
        float CinB = (t == TPR - 1) ? CinitB : fmaf(ea, CinitB, ebB);

        // ---- pass 2: independent fix-up, f shared across rows ----
        #pragma unroll
        for (int qi = CHUNK/4 - 1; qi >= 0; --qi) {
            float4 f4 = f_all[qi];
            const int j = 4*qi;
            if (j + 3 == CHUNK - 1) { ztA = fmaf(f4.w, CinA, ztA);
                                      ztB = fmaf(f4.w, CinB, ztB); }
            else                    { ya[j+4] = fmaf(f4.w, CinA, ya[j+4]);
                                      yb[j+4] = fmaf(f4.w, CinB, yb[j+4]); }
            ya[j+3] = fmaf(f4.z, CinA, ya[j+3]);  yb[j+3] = fmaf(f4.z, CinB, yb[j+3]);
            ya[j+2] = fmaf(f4.y, CinA, ya[j+2]);  yb[j+2] = fmaf(f4.y, CinB, yb[j+2]);
            ya[j+1] = fmaf(f4.x, CinA, ya[j+1]);  yb[j+1] = fmaf(f4.x, CinB, yb[j+1]);
        }

        float upA = __shfl_up(ztA, 1);            // lane t-1's top -> slot 32t
        float upB = __shfl_up(ztB, 1);
        ya[0] = (t == 0) ? zfA : upA;
        yb[0] = (t == 0) ? zfB : upB;
    }

    float4* oa = (float4*)(out + (size_t)B * N_COLS + rowA + t * CHUNK);
    float4* ob = (float4*)(out + (size_t)B * N_COLS + rowB + t * CHUNK);
    #pragma unroll
    for (int i = 0; i < 8; ++i) {
        oa[i] = make_float4(ya[4*i], ya[4*i+1], ya[4*i+2], ya[4*i+3]);
        ob[i] = make_float4(yb[4*i], yb[4*i+1], yb[4*i+2], yb[4*i+3]);
    }
}

// ==================  fallback (self-contained, ws-free)  =================
__global__ __launch_bounds__(256, 2)
void ced_fallback(const float* __restrict__ x,
                  const float* __restrict__ ae,
                  const float* __restrict__ ad,
                  const float* __restrict__ hw,
                  const float* __restrict__ hs,
                  float* __restrict__ out, int B)
{
    __shared__ float2 s_cs[NRINGS * 64 * 16];
    __shared__ float  s_A [NRINGS * 16];
    __shared__ float2 s_aux[NRINGS];

    const int tid = threadIdx.x;
    for (int i = 0; i < 32; ++i) {
        int idx = i * 256 + tid;
        int r   = idx >> 10;
        int k   = idx & 1023;
        const float* ang = (r < 4) ? (ae + (r << 10)) : (ad + ((r - 4) << 10));
        float sv, cv;
        sincosf(ang[k], &sv, &cv);
        int t = k >> 6, j = k & 63;
        float2 e = make_float2(cv, sv);
        if (k == 1023) { s_aux[r] = e; e = make_float2(0.f, -1.f); }
        s_cs[(r * 64 + j) * 16 + t] = e;
    }
    __syncthreads();
    if (tid < NRINGS * 16) {
        int r = tid >> 4, t = tid & 15;
        float p = 1.f;
        for (int j = 0; j < 64; ++j) p *= -s_cs[(r * 64 + j) * 16 + t].y;
        s_A[tid] = p;
    }
    __syncthreads();

    const int lane      = tid & 63;
    const int g         = lane >> 4;
    const int t         = lane & 15;
    const int groupBase = lane & 48;
    const int row       = blockIdx.x * 16 + (tid >> 6) * 4 + g;

    const float* xr = x + (size_t)row * N_COLS + t * 64;
    float y[64];
    #pragma unroll
    for (int i = 0; i < 16; ++i) {
        float4 v = ((const float4*)xr)[i];
        y[4*i] = v.x; y[4*i+1] = v.y; y[4*i+2] = v.z; y[4*i+3] = v.w;
    }
    const float w   = 1.f / (1.f + expf(-hw[0]));
    const float omw = 1.f - w;

    for (int r = 0; r < NRINGS; ++r) {
        if (r == 4) {
            float4* ob = (float4*)(out + (size_t)row * N_COLS + t * 64);
            const float4* hp = (const float4*)(hs + t * 64);
            #pragma unroll
            for (int i = 0; i < 16; ++i) {
                float4 h = hp[i];
                float4 bn;
                bn.x = fmaf(omw, y[4*i+0], w * h.x);
                bn.y = fmaf(omw, y[4*i+1], w * h.y);
                bn.z = fmaf(omw, y[4*i+2], w * h.z);
                bn.w = fmaf(omw, y[4*i+3], w * h.w);
                ob[i] = bn;
                y[4*i+0] = bn.x; y[4*i+1] = bn.y; y[4*i+2] = bn.z; y[4*i+3] = bn.w;
            }
        }
        const float2* csr = s_cs + r * 64 * 16;
        const float2  cN  = s_aux[r];
        float y0 = __shfl(y[0],  groupBase);
        float yN = __shfl(y[63], groupBase + 15);
        float Cinit = cN.x * yN - cN.y * y0;
        float x0n   = fmaf(cN.y, yN, cN.x * y0);
        if (t == 0) y[0] = x0n;

        float carry = 0.f, ztmp = 0.f;
        #pragma unroll
        for (int j = 63; j >= 0; --j) {
            float2 cs = csr[j * 16 + t];
            float z   = fmaf(cs.y, y[j], cs.x * carry);
            carry     = fmaf(-cs.y, carry, cs.x * y[j]);
            if (j == 63) ztmp = z; else y[j + 1] = z;
        }
        float sa = s_A[r * 16 + t], sb = carry;
        #pragma unroll
        for (int d = 1; d < 16; d <<= 1) {
            float a2 = __shfl_down(sa, d);
            float b2 = __shfl_down(sb, d);
            if (t + d < 16) { sb = fmaf(sa, b2, sb); sa *= a2; }
        }
        float ea = __shfl_down(sa, 1);
        float eb = __shfl_down(sb, 1);
        float z0  = fmaf(sa, Cinit, sb);
        float Cin = (t == 15) ? Cinit : fmaf(ea, Cinit, eb);

        float P = 1.f;
        #pragma unroll
        for (int j = 63; j >= 0; --j) {
            float2 cs = csr[j * 16 + t];
            float f = cs.x * P;
            P = -cs.y * P;
            if (j == 63) ztmp = fmaf(f, Cin, ztmp);
            else         y[j + 1] = fmaf(f, Cin, y[j + 1]);
        }
        float up = __shfl_up(ztmp, 1);
        y[0] = (t == 0) ? z0 : up;
    }

    float4* oo = (float4*)(out + (size_t)B * N_COLS + (size_t)row * N_COLS + t * 64);
    #pragma unroll
    for (int i = 0; i < 16; ++i)
        oo[i] = make_float4(y[4*i], y[4*i+1], y[4*i+2], y[4*i+3]);
}

// ============================  launcher  ================================
extern "C" void kernel_launch(void* const* d_in, const int* in_sizes, int n_in,
                              void* d_out, int out_size, void* d_ws, size_t ws_size,
                              hipStream_t stream) {
    const float* x  = (const float*)d_in[0];
    const float* ae = (const float*)d_in[1];
    const float* ad = (const float*)d_in[2];
    const float* hw = (const float*)d_in[3];
    const float* hs = (const float*)d_in[4];
    float* out = (float*)d_out;
    const int B = in_sizes[0] / N_COLS;          // 8192

    if (ws_size >= WS_FLOATS * sizeof(float)) {
        hipLaunchKernelGGL(ced_setup, dim3(32), dim3(256), 0, stream,
                           ae, ad, (float*)d_ws);
        hipLaunchKernelGGL(ced_main, dim3(B / (2 * PAIRS_PER_BLOCK)), dim3(256), 0, stream,
                           x, (const float*)d_ws, hw, hs, out, B);
    } else {
        hipLaunchKernelGGL(ced_fallback, dim3(B / 16), dim3(256), 0, stream,
                           x, ae, ad, hw, hs, out, B);
    }
}

// Round 5
// 124.634 us; speedup vs baseline: 1.1031x; 1.0968x over previous
//
#include <hip/hip_runtime.h>
#include <math.h>

#define N_COLS 1024
#define NRINGS 8

// ---- geometry: 32 threads/row, 32 cols/thread, 2 rows per thread ----
#define TPR    32
#define CHUNK  32
#define PAIRS_PER_BLOCK 8         // 256 threads / 32 lanes-per-pair -> 16 rows/block

// ws layout (floats)
#define F_OFF   16384             // CS: 8*512 float4 = 16384 floats (64 KB)
#define A_OFF   24576             // F : 8*256 float4 =  8192 floats (32 KB)
#define AUX_OFF 24832             // A : 8*32 floats
#define WS_FLOATS 24848           // AUX: 8 float2

// address-space-qualified pointer types for global_load_lds
typedef const __attribute__((address_space(1))) float4* gas_f4;
typedef __attribute__((address_space(3))) void* las_ptr;

// =====================  setup: build angle tables  ======================
// grid = 32 blocks (4 per ring, 256 angles each). 1 sincos per thread.
//   CS  [(r*16 + j/2)*32 + t] : float4 (c_j,s_j,c_{j+1},s_{j+1}), k = t*32+j
//   F   [(r*8  + j/4)*32 + t] : float4 f_j = c_j * prod_{l>j in chunk}(-s_l)
//   A   [r*32 + t]            : prod_j(-s_j) over chunk t
//   AUX [r]                   : real (c,s) at k=1023 (table entry doctored to
//                               (0,-1) = exact no-op chain step)
__global__ __launch_bounds__(256)
void ced_setup(const float* __restrict__ ae,
               const float* __restrict__ ad,
               float* __restrict__ ws)
{
    __shared__ float2 ls[256];
    const int r   = blockIdx.x >> 2;
    const int b   = blockIdx.x & 3;
    const int tid = threadIdx.x;
    const int k   = (b << 8) + tid;
    const float* ang = (r < 4) ? (ae + (r << 10)) : (ad + ((r - 4) << 10));

    float sv, cv;
    sincosf(ang[k], &sv, &cv);
    if (k == N_COLS - 1) {
        ((float2*)(ws + AUX_OFF))[r] = make_float2(cv, sv);
        cv = 0.f; sv = -1.f;              // doctored: no-op step
    }
    ls[tid] = make_float2(cv, sv);
    __syncthreads();

    if (!(tid & 1)) {                     // paired (c,s) table
        float2 e0 = ls[tid], e1 = ls[tid + 1];
        int t  = k >> 5;
        int jp = (k & 31) >> 1;
        ((float4*)ws)[(r*16 + jp)*32 + t] = make_float4(e0.x, e0.y, e1.x, e1.y);
    }

    if (tid < 64) {                       // F and A via 3-round shfl product-scan
        const int lt = tid >> 3;          // local chunk 0..7
        const int q  = tid & 7;           // 4-element sub-segment
        const int t  = (b << 3) + lt;     // global chunk
        const int j0 = lt * CHUNK + 4 * q;
        float2 e0 = ls[j0], e1 = ls[j0+1], e2 = ls[j0+2], e3 = ls[j0+3];

        float f3 = e3.x;       float P = -e3.y;
        float f2 = e2.x * P;   P *= -e2.y;
        float f1 = e1.x * P;   P *= -e1.y;
        float f0 = e0.x * P;   P *= -e0.y;

        float ip = P;                     // inclusive suffix product over segments
        #pragma unroll
        for (int d = 1; d < 8; d <<= 1) {
            float tmp = __shfl_down(ip, d);
            if (q + d < 8) ip *= tmp;
        }
        float ex = __shfl_down(ip, 1);
        if (q == 7) ex = 1.f;
        f0 *= ex; f1 *= ex; f2 *= ex; f3 *= ex;

        ((float4*)(ws + F_OFF))[(r*8 + q)*32 + t] = make_float4(f0, f1, f2, f3);
        if (q == 0) ws[A_OFF + r*TPR + t] = ip;
    }
}

// =====================  main: fused enc->blend->dec  ====================
// R4 failure mode: 208 just-in-time global table loads x ~700cy exposed L2/L3
// latency = the whole 137k-cycle wall. Fix: async-stage ring-pair tables into
// double-buffered LDS with global_load_lds; stage(p+1) issued before compute(p),
// drained by the pair-boundary __syncthreads -> latency hidden behind 2 rings
// of compute. A/AUX staged once (runtime-indexable -> ring loop stays rolled).
__global__ __launch_bounds__(256, 2)
void ced_main(const float* __restrict__ x,
              const float* __restrict__ ws,
              const float* __restrict__ hw,
              const float* __restrict__ hs,
              float* __restrict__ out, int B)
{
    __shared__ float4 sCS[2][1024];   // 2 bufs x (2 rings x 512 float4) = 32 KB
    __shared__ float4 sF [2][512];    // 2 bufs x (2 rings x 256 float4) = 16 KB
    __shared__ float4 sA4[64];        // A: 8*32 floats = 1 KB
    __shared__ float4 sAux4[4];       // AUX: 8 float2

    const float4* CSg = (const float4*)ws;
    const float4* Fg  = (const float4*)(ws + F_OFF);

    const int tid  = threadIdx.x;
    const int lane = tid & 63;
    const int t    = lane & 31;           // chunk index within row
    const int groupBase = lane & 32;
    const int pairRow = blockIdx.x * PAIRS_PER_BLOCK + (tid >> 5);
    const size_t rowA = (size_t)(2 * pairRow) * N_COLS;
    const size_t rowB = rowA + N_COLS;

    // ---- stage ring-pair 0 into buf 0 (async, drained by first sync) ----
    #pragma unroll
    for (int m = 0; m < 4; ++m)
        __builtin_amdgcn_global_load_lds((gas_f4)(CSg + m*256 + tid),
                                         (las_ptr)&sCS[0][m*256 + tid], 16, 0, 0);
    #pragma unroll
    for (int m = 0; m < 2; ++m)
        __builtin_amdgcn_global_load_lds((gas_f4)(Fg + m*256 + tid),
                                         (las_ptr)&sF[0][m*256 + tid], 16, 0, 0);

    // ---- stage A + AUX (once) ----
    if (tid < 64)              sA4[tid]        = ((const float4*)(ws + A_OFF))[tid];
    if (tid >= 64 && tid < 68) sAux4[tid - 64] = ((const float4*)(ws + AUX_OFF))[tid - 64];

    // ---- load x (2 rows) ----
    float ya[CHUNK], yb[CHUNK];
    {
        const float4* xa = (const float4*)(x + rowA + t * CHUNK);
        const float4* xb = (const float4*)(x + rowB + t * CHUNK);
        #pragma unroll
        for (int i = 0; i < 8; ++i) {
            float4 va = xa[i], vb = xb[i];
            ya[4*i] = va.x; ya[4*i+1] = va.y; ya[4*i+2] = va.z; ya[4*i+3] = va.w;
            yb[4*i] = vb.x; yb[4*i+1] = vb.y; yb[4*i+2] = vb.z; yb[4*i+3] = vb.w;
        }
    }

    const float w   = 1.f / (1.f + expf(-hw[0]));
    const float omw = 1.f - w;

    __syncthreads();                      // stage0 + A/AUX visible to all waves

    const float*  As   = (const float*)sA4;
    const float2* Auxs = (const float2*)sAux4;

    #pragma unroll 1
    for (int p = 0; p < 4; ++p) {
        // ---- issue stage(p+1) into the other buffer (async) ----
        if (p < 3) {
            const int nb = (p + 1) & 1;
            const float4* gc = CSg + (p + 1) * 1024;
            const float4* gf = Fg  + (p + 1) * 512;
            #pragma unroll
            for (int m = 0; m < 4; ++m)
                __builtin_amdgcn_global_load_lds((gas_f4)(gc + m*256 + tid),
                                                 (las_ptr)&sCS[nb][m*256 + tid], 16, 0, 0);
            #pragma unroll
            for (int m = 0; m < 2; ++m)
                __builtin_amdgcn_global_load_lds((gas_f4)(gf + m*256 + tid),
                                                 (las_ptr)&sF[nb][m*256 + tid], 16, 0, 0);
        }

        const int buf = p & 1;
        #pragma unroll
        for (int lr = 0; lr < 2; ++lr) {
            const int rr = 2 * p + lr;

            if (p == 2 && lr == 0) {      // bottleneck blend + output 0
                float4* oa = (float4*)(out + rowA + t * CHUNK);
                float4* ob = (float4*)(out + rowB + t * CHUNK);
                const float4* hp = (const float4*)(hs + t * CHUNK);
                #pragma unroll
                for (int i = 0; i < 8; ++i) {
                    float4 h = hp[i];
                    float4 na, nb2;
                    na.x  = fmaf(omw, ya[4*i+0], w * h.x);
                    na.y  = fmaf(omw, ya[4*i+1], w * h.y);
                    na.z  = fmaf(omw, ya[4*i+2], w * h.z);
                    na.w  = fmaf(omw, ya[4*i+3], w * h.w);
                    nb2.x = fmaf(omw, yb[4*i+0], w * h.x);
                    nb2.y = fmaf(omw, yb[4*i+1], w * h.y);
                    nb2.z = fmaf(omw, yb[4*i+2], w * h.z);
                    nb2.w = fmaf(omw, yb[4*i+3], w * h.w);
                    oa[i] = na; ob[i] = nb2;
                    ya[4*i+0] = na.x;  ya[4*i+1] = na.y;  ya[4*i+2] = na.z;  ya[4*i+3] = na.w;
                    yb[4*i+0] = nb2.x; yb[4*i+1] = nb2.y; yb[4*i+2] = nb2.z; yb[4*i+3] = nb2.w;
                }
            }

            const float4* csL = &sCS[buf][lr * 512];   // + jp*32 + t
            const float4* fL  = &sF [buf][lr * 256];   // + qi*32 + t
            const float2  cN  = Auxs[rr];
            const float   saI = As[rr * TPR + t];

            float y0a = __shfl(ya[0],       groupBase);
            float yNa = __shfl(ya[CHUNK-1], groupBase + 31);
            float y0b = __shfl(yb[0],       groupBase);
            float yNb = __shfl(yb[CHUNK-1], groupBase + 31);
            float CinitA = cN.x * yNa - cN.y * y0a;
            float CinitB = cN.x * yNb - cN.y * y0b;
            float x0nA   = fmaf(cN.y, yNa, cN.x * y0a);
            float x0nB   = fmaf(cN.y, yNb, cN.x * y0b);
            if (t == 0) { ya[0] = x0nA; yb[0] = x0nB; }

            // ---- pass 1: two independent local chains (carry_in = 0) ----
            float carA = 0.f, carB = 0.f, ztA = 0.f, ztB = 0.f;
            #pragma unroll
            for (int jp = CHUNK/2 - 1; jp >= 0; --jp) {
                float4 cs4 = csL[jp * 32 + t];        // (c_j0,s_j0,c_j1,s_j1)
                const int j1 = 2*jp + 1;
                float z1a = fmaf(cs4.w, ya[j1], cs4.z * carA);
                float z1b = fmaf(cs4.w, yb[j1], cs4.z * carB);
                carA = fmaf(-cs4.w, carA, cs4.z * ya[j1]);
                carB = fmaf(-cs4.w, carB, cs4.z * yb[j1]);
                if (j1 == CHUNK - 1) { ztA = z1a; ztB = z1b; }
                else                 { ya[j1+1] = z1a; yb[j1+1] = z1b; }
                const int j0 = 2*jp;
                float z0a = fmaf(cs4.y, ya[j0], cs4.x * carA);
                float z0b = fmaf(cs4.y, yb[j0], cs4.x * carB);
                carA = fmaf(-cs4.y, carA, cs4.x * ya[j0]);
                carB = fmaf(-cs4.y, carB, cs4.x * yb[j0]);
                ya[j0+1] = z0a; yb[j0+1] = z0b;
            }

            // ---- affine suffix scan over 32 lanes (sa shared across rows) ----
            float sa = saI;
            float sbA = carA, sbB = carB;
            #pragma unroll
            for (int d = 1; d < TPR; d <<= 1) {
                float a2  = __shfl_down(sa,  d);
                float b2a = __shfl_down(sbA, d);
                float b2b = __shfl_down(sbB, d);
                if (t + d < TPR) {
                    sbA = fmaf(sa, b2a, sbA);
                    sbB = fmaf(sa, b2b, sbB);
                    sa *= a2;
                }
            }
            float ea  = __shfl_down(sa,  1);
            float ebA = __shfl_down(sbA, 1);
            float ebB = __shfl_down(sbB, 1);
            float zfA = fmaf(sa, CinitA, sbA);        // lane0: final z[0]
            float zfB = fmaf(sa, CinitB, sbB);
            float CinA = (t == TPR - 1) ? CinitA : fmaf(ea, CinitA, ebA);
            float CinB = (t == TPR - 1) ? CinitB : fmaf(ea, CinitB, ebB);

            // ---- pass 2: independent fix-up with precomputed f ----
            #pragma unroll
            for (int qi = CHUNK/4 - 1; qi >= 0; --qi) {
                float4 f4 = fL[qi * 32 + t];
                const int j = 4*qi;
                if (j + 3 == CHUNK - 1) { ztA = fmaf(f4.w, CinA, ztA);
                                          ztB = fmaf(f4.w, CinB, ztB); }
                else                    { ya[j+4] = fmaf(f4.w, CinA, ya[j+4]);
                                          yb[j+4] = fmaf(f4.w, CinB, yb[j+4]); }
                ya[j+3] = fmaf(f4.z, CinA, ya[j+3]);  yb[j+3] = fmaf(f4.z, CinB, yb[j+3]);
                ya[j+2] = fmaf(f4.y, CinA, ya[j+2]);  yb[j+2] = fmaf(f4.y, CinB, yb[j+2]);
                ya[j+1] = fmaf(f4.x, CinA, ya[j+1]);  yb[j+1] = fmaf(f4.x, CinB, yb[j+1]);
            }

            float upA = __shfl_up(ztA, 1);            // lane t-1's top -> slot 32t
            float upB = __shfl_up(ztB, 1);
            ya[0] = (t == 0) ? zfA : upA;
            yb[0] = (t == 0) ? zfB : upB;
        }

        // pair boundary: drains stage(p+1) (issued ~2 rings ago) + protects
        // buffer reuse (stage(p+2) overwrites buf p&1 next iteration)
        if (p < 3) __syncthreads();
    }

    float4* oa = (float4*)(out + (size_t)B * N_COLS + rowA + t * CHUNK);
    float4* ob = (float4*)(out + (size_t)B * N_COLS + rowB + t * CHUNK);
    #pragma unroll
    for (int i = 0; i < 8; ++i) {
        oa[i] = make_float4(ya[4*i], ya[4*i+1], ya[4*i+2], ya[4*i+3]);
        ob[i] = make_float4(yb[4*i], yb[4*i+1], yb[4*i+2], yb[4*i+3]);
    }
}

// ==================  fallback (self-contained, ws-free)  =================
__global__ __launch_bounds__(256, 2)
void ced_fallback(const float* __restrict__ x,
                  const float* __restrict__ ae,
                  const float* __restrict__ ad,
                  const float* __restrict__ hw,
                  const float* __restrict__ hs,
                  float* __restrict__ out, int B)
{
    __shared__ float2 s_cs[NRINGS * 64 * 16];
    __shared__ float  s_A [NRINGS * 16];
    __shared__ float2 s_aux[NRINGS];

    const int tid = threadIdx.x;
    for (int i = 0; i < 32; ++i) {
        int idx = i * 256 + tid;
        int r   = idx >> 10;
        int k   = idx & 1023;
        const float* ang = (r < 4) ? (ae + (r << 10)) : (ad + ((r - 4) << 10));
        float sv, cv;
        sincosf(ang[k], &sv, &cv);
        int t = k >> 6, j = k & 63;
        float2 e = make_float2(cv, sv);
        if (k == 1023) { s_aux[r] = e; e = make_float2(0.f, -1.f); }
        s_cs[(r * 64 + j) * 16 + t] = e;
    }
    __syncthreads();
    if (tid < NRINGS * 16) {
        int r = tid >> 4, t = tid & 15;
        float p = 1.f;
        for (int j = 0; j < 64; ++j) p *= -s_cs[(r * 64 + j) * 16 + t].y;
        s_A[tid] = p;
    }
    __syncthreads();

    const int lane      = tid & 63;
    const int g         = lane >> 4;
    const int t         = lane & 15;
    const int groupBase = lane & 48;
    const int row       = blockIdx.x * 16 + (tid >> 6) * 4 + g;

    const float* xr = x + (size_t)row * N_COLS + t * 64;
    float y[64];
    #pragma unroll
    for (int i = 0; i < 16; ++i) {
        float4 v = ((const float4*)xr)[i];
        y[4*i] = v.x; y[4*i+1] = v.y; y[4*i+2] = v.z; y[4*i+3] = v.w;
    }
    const float w   = 1.f / (1.f + expf(-hw[0]));
    const float omw = 1.f - w;

    for (int r = 0; r < NRINGS; ++r) {
        if (r == 4) {
            float4* ob = (float4*)(out + (size_t)row * N_COLS + t * 64);
            const float4* hp = (const float4*)(hs + t * 64);
            #pragma unroll
            for (int i = 0; i < 16; ++i) {
                float4 h = hp[i];
                float4 bn;
                bn.x = fmaf(omw, y[4*i+0], w * h.x);
                bn.y = fmaf(omw, y[4*i+1], w * h.y);
                bn.z = fmaf(omw, y[4*i+2], w * h.z);
                bn.w = fmaf(omw, y[4*i+3], w * h.w);
                ob[i] = bn;
                y[4*i+0] = bn.x; y[4*i+1] = bn.y; y[4*i+2] = bn.z; y[4*i+3] = bn.w;
            }
        }
        const float2* csr = s_cs + r * 64 * 16;
        const float2  cN  = s_aux[r];
        float y0 = __shfl(y[0],  groupBase);
        float yN = __shfl(y[63], groupBase + 15);
        float Cinit = cN.x * yN - cN.y * y0;
        float x0n   = fmaf(cN.y, yN, cN.x * y0);
        if (t == 0) y[0] = x0n;

        float carry = 0.f, ztmp = 0.f;
        #pragma unroll
        for (int j = 63; j >= 0; --j) {
            float2 cs = csr[j * 16 + t];
            float z   = fmaf(cs.y, y[j], cs.x * carry);
            carry     = fmaf(-cs.y, carry, cs.x * y[j]);
            if (j == 63) ztmp = z; else y[j + 1] = z;
        }
        float sa = s_A[r * 16 + t], sb = carry;
        #pragma unroll
        for (int d = 1; d < 16; d <<= 1) {
            float a2 = __shfl_down(sa, d);
            float b2 = __shfl_down(sb, d);
            if (t + d < 16) { sb = fmaf(sa, b2, sb); sa *= a2; }
        }
        float ea = __shfl_down(sa, 1);
        float eb = __shfl_down(sb, 1);
        float z0  = fmaf(sa, Cinit, sb);
        float Cin = (t == 15) ? Cinit : fmaf(ea, Cinit, eb);

        float P = 1.f;
        #pragma unroll
        for (int j = 63; j >= 0; --j) {
            float2 cs = csr[j * 16 + t];
            float f = cs.x * P;
            P = -cs.y * P;
            if (j == 63) ztmp = fmaf(f, Cin, ztmp);
            else         y[j + 1] = fmaf(f, Cin, y[j + 1]);
        }
        float up = __shfl_up(ztmp, 1);
        y[0] = (t == 0) ? z0 : up;
    }

    float4* oo = (float4*)(out + (size_t)B * N_COLS + (size_t)row * N_COLS + t * 64);
    #pragma unroll
    for (int i = 0; i < 16; ++i)
        oo[i] = make_float4(y[4*i], y[4*i+1], y[4*i+2], y[4*i+3]);
}

// ============================  launcher  ================================
extern "C" void kernel_launch(void* const* d_in, const int* in_sizes, int n_in,
                              void* d_out, int out_size, void* d_ws, size_t ws_size,
                              hipStream_t stream) {
    const float* x  = (const float*)d_in[0];
    const float* ae = (const float*)d_in[1];
    const float* ad = (const float*)d_in[2];
    const float* hw = (const float*)d_in[3];
    const float* hs = (const float*)d_in[4];
    float* out = (float*)d_out;
    const int B = in_sizes[0] / N_COLS;          // 8192

    if (ws_size >= WS_FLOATS * sizeof(float)) {
        hipLaunchKernelGGL(ced_setup, dim3(32), dim3(256), 0, stream,
                           ae, ad, (float*)d_ws);
        hipLaunchKernelGGL(ced_main, dim3(B / (2 * PAIRS_PER_BLOCK)), dim3(256), 0, stream,
                           x, (const float*)d_ws, hw, hs, out, B);
    } else {
        hipLaunchKernelGGL(ced_fallback, dim3(B / 16), dim3(256), 0, stream,
                           x, ae, ad, hw, hs, out, B);
    }
}